// Round 13
// baseline (220.589 us; speedup 1.0000x reference)
//
#include <hip/hip_runtime.h>

// ForwardSumLossWithBlank: CTC forward (alpha) loss, blank=0, targets=arange(text_len).
// B=32, T=2000 mel frames, C=400 classes. Output: scalar mean loss (fp32).
//
// Three-tier dispatch on ws_size:
//  F32 path (~131.4 MB): Pass A stores masked NORMALIZED probs as f32 [T][512],
//        permuted pairs (c,c+4) -> pass B's packed update reads ring float4s
//        directly (no bf16 converts). Ring is 8-DEEP (64 VGPR): R12's 16-deep ring
//        (128 VGPR) spilled to scratch (VGPR_Count=132 < 150 needed) and regressed.
//  BF16 path (~66 MB): R10 kernel verbatim (proven: k_ctc 149 us, absmax 0.5).
//  SLOW path: R4 kernels (raw exp(logits), -lsum epilogue).
//
// Cadence model (validated R6-R11): one wave issues ~1 inst / 4 cy; per-step cost =
// instruction count x 4 cy. Optimize instruction count; avoid spills and barriers.

static constexpr int B_ = 32;
static constexpr int T_ = 2000;
static constexpr int C_ = 400;
static constexpr float M0f    = 1e20f;
static constexpr float LOGM0f = 46.05170186f;   // ln(1e20) (fallback path)

typedef float f32x2 __attribute__((ext_vector_type(2)));

template <int CTRL>
__device__ __forceinline__ float dppmov(float v) {
    // mov_dpp, bound_ctrl=1: invalid-source lanes read 0 (safe: alphas >= 0).
    return __int_as_float(__builtin_amdgcn_update_dpp(
        0, __float_as_int(v), CTRL, 0xF, 0xF, true));
}

__device__ __forceinline__ float bcast0(float v) {
    return __int_as_float(__builtin_amdgcn_readfirstlane(__float_as_int(v)));
}

__device__ __forceinline__ unsigned bf16rne(float f) {
    unsigned u = __float_as_uint(f);
    u += 0x7FFFu + ((u >> 16) & 1u);
    return u >> 16;
}

__device__ __forceinline__ f32x2 lo2(const float4 v) { f32x2 r; r.x = v.x; r.y = v.y; return r; }
__device__ __forceinline__ f32x2 hi2(const float4 v) { f32x2 r; r.x = v.z; r.y = v.w; return r; }

// ---------------- Pass A: masked normalized probs ----------------
// mode f32  (pf32!=null): f32 probs, permuted pairs (c,c+4); ls[row] = p0
// mode bf16 (pbf!=null):  bf16 probs, permuted pairs (c,c+4); ls[row] = p0
// mode slow (both null):  ls[row] = ln(sum exp)
__global__ __launch_bounds__(256) void k_prob(const float* __restrict__ logits,
                                              const int* __restrict__ text_lens,
                                              float* __restrict__ pf32,
                                              unsigned short* __restrict__ pbf,
                                              float* __restrict__ ls) {
    const int lane = threadIdx.x & 63;
    const int row  = blockIdx.x * 4 + (threadIdx.x >> 6);   // grid = B*T/4 exactly
    const int b    = row / T_;
    const int tl   = text_lens[b];
    const float* __restrict__ r = logits + (size_t)row * C_;

    const int c0 = lane * 8;
    float v[8];
    if (c0 < C_) {           // row is 1600 B, 16B-aligned; lane<50 reads [c0, c0+8)
        const float4 a = *(const float4*)(r + c0);
        const float4 c = *(const float4*)(r + c0 + 4);
        v[0]=a.x; v[1]=a.y; v[2]=a.z; v[3]=a.w; v[4]=c.x; v[5]=c.y; v[6]=c.z; v[7]=c.w;
    } else {
#pragma unroll
        for (int e = 0; e < 8; ++e) v[e] = 0.f;             // masked below anyway
    }
    float ex[8]; float s = 0.f;
#pragma unroll
    for (int e = 0; e < 8; ++e) {
        const int c = c0 + e;
        const float t = (c < tl) ? __expf(v[e]) : 0.f;      // tl <= 400 -> cols>=400 masked
        ex[e] = t; s += t;
    }
#pragma unroll
    for (int off = 32; off; off >>= 1) s += __shfl_xor(s, off);

    if (pf32) {
        const float inv = 1.0f / s;
        // permuted: slot j = pairs (c0+j, c0+j+4); lane's 8 floats at row*512 + c0
        float4 s0, s1;
        s0.x = ex[0]*inv; s0.y = ex[4]*inv; s0.z = ex[1]*inv; s0.w = ex[5]*inv;
        s1.x = ex[2]*inv; s1.y = ex[6]*inv; s1.z = ex[3]*inv; s1.w = ex[7]*inv;
        float* dst = pf32 + (size_t)row * 512 + c0;
        *(float4*)dst = s0;
        *(float4*)(dst + 4) = s1;
        if (lane == 0) ls[row] = ex[0] * inv;               // p0 (col 0 always < tl)
    } else if (pbf) {
        const float inv = 1.0f / s;
        // R10 layout: dword j = (col c0+j, col c0+j+4)
        uint4 st;
        st.x = bf16rne(ex[0]*inv) | (bf16rne(ex[4]*inv) << 16);
        st.y = bf16rne(ex[1]*inv) | (bf16rne(ex[5]*inv) << 16);
        st.z = bf16rne(ex[2]*inv) | (bf16rne(ex[6]*inv) << 16);
        st.w = bf16rne(ex[3]*inv) | (bf16rne(ex[7]*inv) << 16);
        *(uint4*)(pbf + (size_t)row * 512 + c0) = st;
        if (lane == 0) ls[row] = ex[0] * inv;
    } else {
        if (lane == 0) ls[row] = __logf(s);
    }
}

// ---------------- Pass A2 (slow path only): per-sample sum of ln-denominators ----------------
__global__ __launch_bounds__(256) void k_lsum(const float* __restrict__ ls,
                                              const int* __restrict__ mel_lens,
                                              float* __restrict__ lsums) {
    const int b  = blockIdx.x;
    const int ml = mel_lens[b];
    float s = 0.f;
    for (int i = threadIdx.x; i < ml; i += 256) s += ls[(size_t)b * T_ + i];
#pragma unroll
    for (int off = 32; off; off >>= 1) s += __shfl_xor(s, off);
    __shared__ float ws[4];
    if ((threadIdx.x & 63) == 0) ws[threadIdx.x >> 6] = s;
    __syncthreads();
    if (threadIdx.x == 0) lsums[b] = (ws[0] + ws[1]) + (ws[2] + ws[3]);
}

// ---------------- shared packed pieces ----------------
// Slot j holds CTC pairs (lane*8+j, lane*8+4+j) as float2 (X=low, Y=high).
__device__ __forceinline__ void renorm_exp_pk(f32x2* __restrict__ Ae,
                                              f32x2* __restrict__ Ao, int& exacc) {
    const f32x2 m0 = __builtin_elementwise_max(__builtin_elementwise_max(Ae[0], Ao[0]),
                                               __builtin_elementwise_max(Ae[1], Ao[1]));
    const f32x2 m1 = __builtin_elementwise_max(__builtin_elementwise_max(Ae[2], Ao[2]),
                                               __builtin_elementwise_max(Ae[3], Ao[3]));
    const f32x2 m2 = __builtin_elementwise_max(m0, m1);
    float m = fmaxf(m2.x, m2.y);
    m = fmaxf(m, dppmov<0x111>(m));   // row_shr:1
    m = fmaxf(m, dppmov<0x112>(m));   // row_shr:2
    m = fmaxf(m, dppmov<0x114>(m));   // row_shr:4
    m = fmaxf(m, dppmov<0x118>(m));   // row_shr:8
    m = fmaxf(m, dppmov<0x142>(m));   // row_bcast:15
    m = fmaxf(m, dppmov<0x143>(m));   // row_bcast:31 -> lane 63 holds wave max
    const int wmb = __builtin_amdgcn_readlane(__float_as_int(m), 63);
    int ex = ((wmb >> 23) & 0xFF) - 127;
    if (ex < -60) ex = -60;                 // guard vs denorm/zero max
    exacc += ex - 66;
    const float scale = __int_as_float((unsigned)(193 - ex) << 23);  // 2^(66-ex), exact
    const f32x2 sc = {scale, scale};
#pragma unroll
    for (int j = 0; j < 4; ++j) { Ae[j] *= sc; Ao[j] *= sc; }
}

__device__ __forceinline__ void update_pk(const float p0,
                                          const f32x2 pk0, const f32x2 pk1,
                                          const f32x2 pk2, const f32x2 pk3,
                                          f32x2* __restrict__ Ae, f32x2* __restrict__ Ao) {
    const float bnd = dppmov<0x138>(Ao[3].y);   // wave_shr:1; lane0 reads 0
    f32x2 prev0; prev0.x = bnd; prev0.y = Ao[3].x;
    const f32x2 E0 = Ae[0] + prev0;
    const f32x2 E1 = Ae[1] + Ao[0];
    const f32x2 E2 = Ae[2] + Ao[1];
    const f32x2 E3 = Ae[3] + Ao[2];
    const f32x2 T0 = Ao[0] + E0;
    const f32x2 T1 = Ao[1] + E1;
    const f32x2 T2 = Ao[2] + E2;
    const f32x2 T3 = Ao[3] + E3;
    const f32x2 vp0 = {p0, p0};
    Ae[0] = E0 * vp0; Ae[1] = E1 * vp0; Ae[2] = E2 * vp0; Ae[3] = E3 * vp0;
    Ao[0] = T0 * pk0; Ao[1] = T1 * pk1; Ao[2] = T2 * pk2; Ao[3] = T3 * pk3;
}

// ---------------- Pass B (F32 path): f32 prob ring (8-deep), zero converts ----------------
__global__ __launch_bounds__(64) void k_ctc_f32(const float* __restrict__ pf32,
                                                const int* __restrict__ text_lens,
                                                const int* __restrict__ mel_lens,
                                                const float* __restrict__ p0arr,
                                                float* __restrict__ losses) {
    const int b    = blockIdx.x;
    const int lane = threadIdx.x;
    const int tl   = text_lens[b];
    const int ml   = mel_lens[b];
    const float4* __restrict__ basef = (const float4*)(pf32 + (size_t)b * T_ * 512); // 128/row
    const float* __restrict__ p0b    = p0arr + (size_t)b * T_;

    // 8-slot ring (64 VGPR), 2 float4 per slot; invariant: row r lives in slot r&7.
    // Prologue: rows 1..8 -> slots 1..7,0 (ml >= 1024).
    float4 rawA[8], rawB[8];
#pragma unroll
    for (int s = 1; s <= 8; ++s) {
        const float4* __restrict__ rowp = basef + (size_t)s * 128;
        rawA[s & 7] = rowp[2 * lane]; rawB[s & 7] = rowp[2 * lane + 1];
    }

    f32x2 Ae[4], Ao[4];
#pragma unroll
    for (int j = 0; j < 4; ++j) { Ae[j] = (f32x2){0.f, 0.f}; Ao[j] = (f32x2){0.f, 0.f}; }
    {   // alpha0[0] = alpha0[1] = p(t=0, class 0), pre-scaled by 2^66; pair 0 = slot0.x
        const float p00 = p0b[0] * 0x1p66f;
        if (lane == 0) { Ae[0].x = p00; Ao[0].x = p00; }
    }
    int exacc = -66;                  // lognorm = exacc * ln2 at the end
    float p0A = p0b[1], p0B = p0b[2]; // scalar p0 pipeline, 2 steps ahead

    // Step I (t = tb+I, tb == 1 mod 16): reload slot (t-1)&7 with row t+7 (consumed
    // 8 steps later from slot (t+7)&7 == (t-1)&7), consume slot t&7, refill p0 t+2.
#define STEPF(I, P0IN, CLAMPED)                                                 \
    {                                                                           \
        constexpr int Sc = (1 + (I)) & 7;                                       \
        constexpr int Sl = (I) & 7;                                             \
        const int t = tb + (I);                                                 \
        { int tr = t + 7; if (CLAMPED) { if (tr > ml - 1) tr = ml - 1; }        \
          const float4* __restrict__ rowp = basef + (size_t)tr * 128;           \
          rawA[Sl] = rowp[2 * lane]; rawB[Sl] = rowp[2 * lane + 1]; }           \
        update_pk(P0IN, lo2(rawA[Sc]), hi2(rawA[Sc]),                           \
                        lo2(rawB[Sc]), hi2(rawB[Sc]), Ae, Ao);                  \
        { int t2 = t + 2; if (CLAMPED) { if (t2 > ml - 1) t2 = ml - 1; }        \
          P0IN = p0b[t2]; }                                                     \
        if (((I) & 7) == 7) renorm_exp_pk(Ae, Ao, exacc);                       \
    }

#define BLOCKF(CLAMPED)                                                         \
        STEPF(0,  p0A, CLAMPED)  STEPF(1,  p0B, CLAMPED)                        \
        STEPF(2,  p0A, CLAMPED)  STEPF(3,  p0B, CLAMPED)                        \
        STEPF(4,  p0A, CLAMPED)  STEPF(5,  p0B, CLAMPED)                        \
        STEPF(6,  p0A, CLAMPED)  STEPF(7,  p0B, CLAMPED)                        \
        STEPF(8,  p0A, CLAMPED)  STEPF(9,  p0B, CLAMPED)                        \
        STEPF(10, p0A, CLAMPED)  STEPF(11, p0B, CLAMPED)                        \
        STEPF(12, p0A, CLAMPED)  STEPF(13, p0B, CLAMPED)                        \
        STEPF(14, p0A, CLAMPED)  STEPF(15, p0B, CLAMPED)

    int tb = 1;
    for (; tb + 23 <= ml; tb += 16) {       // steady: max load row tb+22 <= ml-1
        BLOCKF(0)
    }
    if (tb + 16 <= ml) {                    // one transition block with clamped loads
        BLOCKF(1)
        tb += 16;
    }

    // tail: steps tb..ml-1 (<16). Ring holds rows tb..tb+6; tail reloads (clamped,
    // never consumed when clamped) cover rows tb+7..; no renorm (<=15 steps of
    // shrink-only drift stays in fp32 range).
#define STEPF_TAIL(I, P0IN)                                                     \
    if (tb + (I) < ml) {                                                        \
        constexpr int Sc = (1 + (I)) & 7;                                       \
        constexpr int Sl = (I) & 7;                                             \
        { int tr = tb + (I) + 7; if (tr > ml - 1) tr = ml - 1;                  \
          const float4* __restrict__ rowp = basef + (size_t)tr * 128;           \
          rawA[Sl] = rowp[2 * lane]; rawB[Sl] = rowp[2 * lane + 1]; }           \
        update_pk(P0IN, lo2(rawA[Sc]), hi2(rawA[Sc]),                           \
                        lo2(rawB[Sc]), hi2(rawB[Sc]), Ae, Ao);                  \
        { int t2 = tb + (I) + 2; if (t2 > ml - 1) t2 = ml - 1;                  \
          P0IN = p0b[t2]; }                                                     \
    }
    STEPF_TAIL(0,  p0A)  STEPF_TAIL(1,  p0B)
    STEPF_TAIL(2,  p0A)  STEPF_TAIL(3,  p0B)
    STEPF_TAIL(4,  p0A)  STEPF_TAIL(5,  p0B)
    STEPF_TAIL(6,  p0A)  STEPF_TAIL(7,  p0B)
    STEPF_TAIL(8,  p0A)  STEPF_TAIL(9,  p0B)
    STEPF_TAIL(10, p0A)  STEPF_TAIL(11, p0B)
    STEPF_TAIL(12, p0A)  STEPF_TAIL(13, p0B)
    STEPF_TAIL(14, p0A)  STEPF_TAIL(15, p0B)
#undef STEPF_TAIL
#undef BLOCKF
#undef STEPF

    // epilogue: probs normalized -> ll = ln(contrib) + exacc*ln2
    float contrib = 0.f;
#pragma unroll
    for (int j = 0; j < 4; ++j) {
        const int kx = lane * 8 + j;
        const int ky = kx + 4;
        if (kx == tl)     contrib += Ae[j].x;
        if (kx == tl - 1) contrib += Ao[j].x;
        if (ky == tl)     contrib += Ae[j].y;
        if (ky == tl - 1) contrib += Ao[j].y;
    }
#pragma unroll
    for (int off = 32; off; off >>= 1) contrib += __shfl_xor(contrib, off);
    if (lane == 0) {
        float loss = 0.f;
        if (contrib > 0.f) {
            const float ll = __logf(contrib) + (float)exacc * 0.69314718056f;
            loss = -ll / (float)tl;
        }
        losses[b] = loss;
    }
}

// ---------------- Pass B (BF16 path): R10 kernel verbatim ----------------
__global__ __launch_bounds__(64) void k_ctc_bf16(const unsigned short* __restrict__ pbf,
                                                 const int* __restrict__ text_lens,
                                                 const int* __restrict__ mel_lens,
                                                 const float* __restrict__ p0arr,
                                                 float* __restrict__ losses) {
    const int b    = blockIdx.x;
    const int lane = threadIdx.x;
    const int tl   = text_lens[b];
    const int ml   = mel_lens[b];
    const unsigned short* __restrict__ pb = pbf + (size_t)b * T_ * 512;
    const uint4* __restrict__ base = (const uint4*)pb;       // 64 uint4 per row
    const float* __restrict__ p0b  = p0arr + (size_t)b * T_;

    uint4 raw[16];
#pragma unroll
    for (int s = 0; s < 16; ++s) {
        const uint4* __restrict__ rowp = base + (size_t)(s + 1) * 64;
        raw[s] = rowp[lane];
    }

    f32x2 Ae[4], Ao[4];
#pragma unroll
    for (int j = 0; j < 4; ++j) { Ae[j] = (f32x2){0.f, 0.f}; Ao[j] = (f32x2){0.f, 0.f}; }
    {
        const float p00 = p0b[0] * 0x1p66f;
        if (lane == 0) { Ae[0].x = p00; Ao[0].x = p00; }
    }
    int exacc = -66;

#define CVT8(SLOT, P)  { const uint4 w = raw[SLOT];                                   \
        P[0].x=__uint_as_float(w.x<<16); P[0].y=__uint_as_float(w.x&0xFFFF0000u);     \
        P[1].x=__uint_as_float(w.y<<16); P[1].y=__uint_as_float(w.y&0xFFFF0000u);     \
        P[2].x=__uint_as_float(w.z<<16); P[2].y=__uint_as_float(w.z&0xFFFF0000u);     \
        P[3].x=__uint_as_float(w.w<<16); P[3].y=__uint_as_float(w.w&0xFFFF0000u); }

    f32x2 pA[4], pB[4];
    float p0A = p0b[1], p0B = p0b[2];
    CVT8(0, pA)

#define STEP_MAIN(S, PIN, P0IN, POUT, CLAMPED)                                 \
    { int tr = tb + (S) + 16;                                                  \
      if (CLAMPED) { if (tr > ml - 1) tr = ml - 1; }                           \
      const uint4* __restrict__ rowp = base + (size_t)tr * 64;                 \
      raw[S] = rowp[lane]; }                                                   \
    CVT8(((S) + 1) & 15, POUT)                                                 \
    update_pk(P0IN, PIN[0], PIN[1], PIN[2], PIN[3], Ae, Ao);                   \
    { int t2 = tb + (S) + 2;                                                   \
      if (CLAMPED) { if (t2 > ml - 1) t2 = ml - 1; }                           \
      P0IN = p0b[t2]; }                                                        \
    if (((S) & 7) == 7) renorm_exp_pk(Ae, Ao, exacc);

#define BLOCK16(CLAMPED)                                                       \
        STEP_MAIN(0,  pA, p0A, pB, CLAMPED)                                    \
        STEP_MAIN(1,  pB, p0B, pA, CLAMPED)                                    \
        STEP_MAIN(2,  pA, p0A, pB, CLAMPED)                                    \
        STEP_MAIN(3,  pB, p0B, pA, CLAMPED)                                    \
        STEP_MAIN(4,  pA, p0A, pB, CLAMPED)                                    \
        STEP_MAIN(5,  pB, p0B, pA, CLAMPED)                                    \
        STEP_MAIN(6,  pA, p0A, pB, CLAMPED)                                    \
        STEP_MAIN(7,  pB, p0B, pA, CLAMPED)                                    \
        STEP_MAIN(8,  pA, p0A, pB, CLAMPED)                                    \
        STEP_MAIN(9,  pB, p0B, pA, CLAMPED)                                    \
        STEP_MAIN(10, pA, p0A, pB, CLAMPED)                                    \
        STEP_MAIN(11, pB, p0B, pA, CLAMPED)                                    \
        STEP_MAIN(12, pA, p0A, pB, CLAMPED)                                    \
        STEP_MAIN(13, pB, p0B, pA, CLAMPED)                                    \
        STEP_MAIN(14, pA, p0A, pB, CLAMPED)                                    \
        STEP_MAIN(15, pB, p0B, pA, CLAMPED)

    int tb = 1;
    for (; tb + 32 <= ml; tb += 16) {
        BLOCK16(0)
    }
    if (tb + 16 <= ml) {
        BLOCK16(1)
        tb += 16;
    }

#define STEP_TAIL(S, PIN, P0IN, POUT)                                          \
    if (tb + (S) < ml) {                                                       \
        CVT8(((S) + 1) & 15, POUT)                                             \
        update_pk(P0IN, PIN[0], PIN[1], PIN[2], PIN[3], Ae, Ao);               \
        { int t2 = tb + (S) + 2; if (t2 > ml - 1) t2 = ml - 1;                 \
          P0IN = p0b[t2]; }                                                    \
    }
    STEP_TAIL(0,  pA, p0A, pB)
    STEP_TAIL(1,  pB, p0B, pA)
    STEP_TAIL(2,  pA, p0A, pB)
    STEP_TAIL(3,  pB, p0B, pA)
    STEP_TAIL(4,  pA, p0A, pB)
    STEP_TAIL(5,  pB, p0B, pA)
    STEP_TAIL(6,  pA, p0A, pB)
    STEP_TAIL(7,  pB, p0B, pA)
    STEP_TAIL(8,  pA, p0A, pB)
    STEP_TAIL(9,  pB, p0B, pA)
    STEP_TAIL(10, pA, p0A, pB)
    STEP_TAIL(11, pB, p0B, pA)
    STEP_TAIL(12, pA, p0A, pB)
    STEP_TAIL(13, pB, p0B, pA)
    STEP_TAIL(14, pA, p0A, pB)
    STEP_TAIL(15, pB, p0B, pA)
#undef STEP_TAIL
#undef BLOCK16
#undef STEP_MAIN
#undef CVT8

    float contrib = 0.f;
#pragma unroll
    for (int j = 0; j < 4; ++j) {
        const int kx = lane * 8 + j;
        const int ky = kx + 4;
        if (kx == tl)     contrib += Ae[j].x;
        if (kx == tl - 1) contrib += Ao[j].x;
        if (ky == tl)     contrib += Ae[j].y;
        if (ky == tl - 1) contrib += Ao[j].y;
    }
#pragma unroll
    for (int off = 32; off; off >>= 1) contrib += __shfl_xor(contrib, off);
    if (lane == 0) {
        float loss = 0.f;
        if (contrib > 0.f) {
            const float ll = __logf(contrib) + (float)exacc * 0.69314718056f;
            loss = -ll / (float)tl;
        }
        losses[b] = loss;
    }
}

// ---------------- Pass B (slow fallback, proven R4): direct logit loads ----------------
template <int PP>
__device__ __forceinline__ void step_update(const float p0, const float* __restrict__ p,
                                            float* __restrict__ aeven, float* __restrict__ aodd) {
    float prev = dppmov<0x138>(aodd[PP - 1]);
#pragma unroll
    for (int j = 0; j < PP; ++j) {
        const float oldodd = aodd[j];
        const float e = aeven[j] + prev;
        aeven[j] = e * p0;
        aodd[j]  = (oldodd + e) * p[j];
        prev = oldodd;
    }
}

template <int PP>
__device__ __forceinline__ void renorm(float* __restrict__ aeven, float* __restrict__ aodd,
                                       float& lognorm) {
    float m = 0.f;
#pragma unroll
    for (int j = 0; j < PP; ++j) m = fmaxf(m, fmaxf(aeven[j], aodd[j]));
    m = fmaxf(m, dppmov<0x111>(m));
    m = fmaxf(m, dppmov<0x112>(m));
    m = fmaxf(m, dppmov<0x114>(m));
    m = fmaxf(m, dppmov<0x118>(m));
    m = fmaxf(m, dppmov<0x142>(m));
    m = fmaxf(m, dppmov<0x143>(m));
    const float wm  = __int_as_float(__builtin_amdgcn_readlane(__float_as_int(m), 63));
    const float inv = 1.0f / wm;
    lognorm += __logf(wm) - LOGM0f;
#pragma unroll
    for (int j = 0; j < PP; ++j) {
        aeven[j] = (aeven[j] * inv) * M0f;
        aodd[j]  = (aodd[j]  * inv) * M0f;
    }
}

template <int PP>
__device__ __forceinline__ void ctc_run_slow(const float* __restrict__ Lb, float lsum,
                                             int tl, int ml, float* __restrict__ loss_out) {
    const int lane = threadIdx.x;
    const int base = lane * PP;
    int   idx[PP];
    float mask[PP];
#pragma unroll
    for (int j = 0; j < PP; ++j) {
        const int k = base + j;
        idx[j]  = (k < C_) ? k : (C_ - 1);
        mask[j] = (k < tl) ? 1.f : 0.f;
    }
    float raw[8][PP];
#pragma unroll
    for (int s = 0; s < 8; ++s) {
        const float* __restrict__ rowp = Lb + (size_t)(s + 1) * C_;
#pragma unroll
        for (int j = 0; j < PP; ++j) raw[s][j] = rowp[idx[j]];
    }
    float aeven[PP], aodd[PP];
#pragma unroll
    for (int j = 0; j < PP; ++j) { aeven[j] = 0.f; aodd[j] = 0.f; }
    {
        const float a00 = __expf(Lb[0]) * M0f;
        if (lane == 0) { aeven[0] = a00; aodd[0] = a00; }
    }
    float lognorm = -LOGM0f;
    int tb = 1;
    for (; tb + 8 <= ml; tb += 8) {
#pragma unroll
        for (int s = 0; s < 8; ++s) {
            const int tt = tb + s;
            const float p0 = __expf(bcast0(raw[s][0]));
            float p[PP];
#pragma unroll
            for (int j = 0; j < PP; ++j) p[j] = __expf(raw[s][j]) * mask[j];
            { int tr = tt + 8; if (tr > ml - 1) tr = ml - 1;
              const float* __restrict__ rowp = Lb + (size_t)tr * C_;
#pragma unroll
              for (int j = 0; j < PP; ++j) raw[s][j] = rowp[idx[j]]; }
            step_update<PP>(p0, p, aeven, aodd);
            if (s == 7) renorm<PP>(aeven, aodd, lognorm);
        }
    }
#pragma unroll
    for (int s = 0; s < 8; ++s) {
        const int tt = tb + s;
        if (tt < ml) {
            const float p0 = __expf(bcast0(raw[s][0]));
            float p[PP];
#pragma unroll
            for (int j = 0; j < PP; ++j) p[j] = __expf(raw[s][j]) * mask[j];
            step_update<PP>(p0, p, aeven, aodd);
            if (s == 7) renorm<PP>(aeven, aodd, lognorm);
        }
    }
    float contrib = 0.f;
#pragma unroll
    for (int j = 0; j < PP; ++j) {
        const int k = base + j;
        if (k == tl)     contrib += aeven[j];
        if (k == tl - 1) contrib += aodd[j];
    }
#pragma unroll
    for (int off = 32; off; off >>= 1) contrib += __shfl_xor(contrib, off);
    if (lane == 0) {
        float loss = 0.f;
        if (contrib > 0.f) {
            const float ll = __logf(contrib) + lognorm - lsum;   // raw domain: -lsum needed
            loss = -ll / (float)tl;
        }
        *loss_out = loss;
    }
}

__global__ __launch_bounds__(64) void k_ctc_slow(const float* __restrict__ logits,
                                                 const int* __restrict__ text_lens,
                                                 const int* __restrict__ mel_lens,
                                                 const float* __restrict__ lsums,
                                                 float* __restrict__ losses) {
    const int b  = blockIdx.x;
    const int tl = text_lens[b];
    const int ml = mel_lens[b];
    const float lsum = lsums[b];
    const float* Lb = logits + (size_t)b * T_ * C_;
    float* lo = losses + b;
    const int PP = (tl + 1 + 63) >> 6;
    switch (PP) {
        case 1: ctc_run_slow<1>(Lb, lsum, tl, ml, lo); break;
        case 2: ctc_run_slow<2>(Lb, lsum, tl, ml, lo); break;
        case 3: ctc_run_slow<3>(Lb, lsum, tl, ml, lo); break;
        case 4: ctc_run_slow<4>(Lb, lsum, tl, ml, lo); break;
        case 5: ctc_run_slow<5>(Lb, lsum, tl, ml, lo); break;
        case 6: ctc_run_slow<6>(Lb, lsum, tl, ml, lo); break;
        default: ctc_run_slow<7>(Lb, lsum, tl, ml, lo); break;
    }
}

// ---------------- Pass C: deterministic mean ----------------
__global__ __launch_bounds__(64) void k_final(const float* __restrict__ losses,
                                              float* __restrict__ out) {
    const int lane = threadIdx.x;
    float v = (lane < B_) ? losses[lane] : 0.f;
#pragma unroll
    for (int off = 32; off; off >>= 1) v += __shfl_xor(v, off);
    if (lane == 0) out[0] = v * (1.0f / B_);
}

extern "C" void kernel_launch(void* const* d_in, const int* in_sizes, int n_in,
                              void* d_out, int out_size, void* d_ws, size_t ws_size,
                              hipStream_t stream) {
    const float* logits    = (const float*)d_in[0];   // [B,1,T,C] fp32
    const int*   text_lens = (const int*)d_in[1];     // [B] int32
    const int*   mel_lens  = (const int*)d_in[2];     // [B] int32
    float* out = (float*)d_out;

    const size_t PF32_BYTES = (size_t)B_ * T_ * 512 * 4;          // 131,072,000
    const size_t PBF_BYTES  = (size_t)B_ * T_ * 512 * 2;          //  65,536,000
    const size_t tail_bytes = (size_t)B_ * T_ * 4 + 2 * B_ * 4 + 64;

    if (ws_size >= PF32_BYTES + tail_bytes) {
        float* pf32   = (float*)d_ws;
        float* ls     = (float*)((char*)d_ws + PF32_BYTES);   // p0[t]
        float* lsums  = ls + (size_t)B_ * T_;
        float* losses = lsums + B_;
        k_prob<<<B_ * T_ / 4, 256, 0, stream>>>(logits, text_lens, pf32, nullptr, ls);
        k_ctc_f32<<<B_, 64, 0, stream>>>(pf32, text_lens, mel_lens, ls, losses);
        k_final<<<1, 64, 0, stream>>>(losses, out);
    } else if (ws_size >= PBF_BYTES + tail_bytes) {
        unsigned short* pbf = (unsigned short*)d_ws;
        float* ls     = (float*)((char*)d_ws + PBF_BYTES);    // p0[t]
        float* lsums  = ls + (size_t)B_ * T_;
        float* losses = lsums + B_;
        k_prob<<<B_ * T_ / 4, 256, 0, stream>>>(logits, text_lens, nullptr, pbf, ls);
        k_ctc_bf16<<<B_, 64, 0, stream>>>(pbf, text_lens, mel_lens, ls, losses);
        k_final<<<1, 64, 0, stream>>>(losses, out);
    } else {
        float* ls     = (float*)d_ws;
        float* lsums  = ls + (size_t)B_ * T_;
        float* losses = lsums + B_;
        k_prob<<<B_ * T_ / 4, 256, 0, stream>>>(logits, text_lens, nullptr, nullptr, ls);
        k_lsum<<<B_, 256, 0, stream>>>(ls, mel_lens, lsums);
        k_ctc_slow<<<B_, 64, 0, stream>>>(logits, text_lens, mel_lens, lsums, losses);
        k_final<<<1, 64, 0, stream>>>(losses, out);
    }
}

// Round 14
// 180.280 us; speedup vs baseline: 1.2236x; 1.2236x over previous
//
#include <hip/hip_runtime.h>

// ForwardSumLossWithBlank: CTC forward (alpha) loss, blank=0, targets=arange(text_len).
// B=32, T=2000 mel frames, C=400 classes. Output: scalar mean loss (fp32).
//
// FAST path (needs ~66 MB of d_ws) — bf16 probs (L2-resident: 2 MB/sample):
//   Pass A (k_prob): masked NORMALIZED probs -> bf16 [T][512] in ws, permuted pairs
//          (c,c+4) for the packed recursion; ls[row] = p0[row] (f32).
//   Pass B (k_ctc_bf16): one wave per sample, 8 pairs/lane as 4 x f32x2 slots.
//          Per step: ONE saddr+imm global_load_dwordx4 (16-deep ring, 32-bit block-
//          uniform addressing), 8 bf16 converts pipelined one step ahead, 16 packed
//          VOP3P update + 1 DPP; p0 block-batched into SGPRs (16/scalar-load-group,
//          prefetched one block ahead). Renorm every 8 steps, exponent-only.
//   Pass C (k_final): deterministic mean.
// SLOW path: R4 kernels (raw exp(logits), -lsum epilogue).
//
// History: R11 2-wave split regressed (barriers ~120cy/step); R12/R13 f32 probs
// regressed (4.1MB/sample thrashes 4MB/XCD L2 -> latency-bound; bf16 is L2-resident
// and cadence-saturated at 0.25 inst/cy). Cadence model: 1 wave ~ 1 inst / 4 cy.

static constexpr int B_ = 32;
static constexpr int T_ = 2000;
static constexpr int C_ = 400;
static constexpr float M0f    = 1e20f;
static constexpr float LOGM0f = 46.05170186f;   // ln(1e20) (fallback path)

typedef float f32x2 __attribute__((ext_vector_type(2)));
typedef float f32x8v __attribute__((ext_vector_type(8)));
struct __attribute__((packed, aligned(4))) f32x8u { f32x8v v; };   // 4B-aligned scalar block load

template <int CTRL>
__device__ __forceinline__ float dppmov(float v) {
    // mov_dpp, bound_ctrl=1: invalid-source lanes read 0 (safe: alphas >= 0).
    return __int_as_float(__builtin_amdgcn_update_dpp(
        0, __float_as_int(v), CTRL, 0xF, 0xF, true));
}

__device__ __forceinline__ float bcast0(float v) {
    return __int_as_float(__builtin_amdgcn_readfirstlane(__float_as_int(v)));
}

__device__ __forceinline__ unsigned bf16rne(float f) {
    unsigned u = __float_as_uint(f);
    u += 0x7FFFu + ((u >> 16) & 1u);
    return u >> 16;
}

// ---------------- Pass A: masked normalized probs (bf16, padded 512, permuted) ----------------
// fast (pbf!=null): ls[row] = p0 (f32 normalized blank prob); slow: ls[row] = ln(sum exp)
__global__ __launch_bounds__(256) void k_prob(const float* __restrict__ logits,
                                              const int* __restrict__ text_lens,
                                              unsigned short* __restrict__ pbf,
                                              float* __restrict__ ls) {
    const int lane = threadIdx.x & 63;
    const int row  = blockIdx.x * 4 + (threadIdx.x >> 6);   // grid = B*T/4 exactly
    const int b    = row / T_;
    const int tl   = text_lens[b];
    const float* __restrict__ r = logits + (size_t)row * C_;

    const int c0 = lane * 8;
    float v[8];
    if (c0 < C_) {           // row is 1600 B, 16B-aligned; lane<50 reads [c0, c0+8)
        const float4 a = *(const float4*)(r + c0);
        const float4 c = *(const float4*)(r + c0 + 4);
        v[0]=a.x; v[1]=a.y; v[2]=a.z; v[3]=a.w; v[4]=c.x; v[5]=c.y; v[6]=c.z; v[7]=c.w;
    } else {
#pragma unroll
        for (int e = 0; e < 8; ++e) v[e] = 0.f;             // masked below anyway
    }
    float ex[8]; float s = 0.f;
#pragma unroll
    for (int e = 0; e < 8; ++e) {
        const int c = c0 + e;
        const float t = (c < tl) ? __expf(v[e]) : 0.f;      // tl <= 400 -> cols>=400 masked
        ex[e] = t; s += t;
    }
#pragma unroll
    for (int off = 32; off; off >>= 1) s += __shfl_xor(s, off);

    if (pbf) {
        const float inv = 1.0f / s;
        // permuted: dword j = (col c0+j, col c0+j+4) = packed slot j
        uint4 st;
        st.x = bf16rne(ex[0]*inv) | (bf16rne(ex[4]*inv) << 16);
        st.y = bf16rne(ex[1]*inv) | (bf16rne(ex[5]*inv) << 16);
        st.z = bf16rne(ex[2]*inv) | (bf16rne(ex[6]*inv) << 16);
        st.w = bf16rne(ex[3]*inv) | (bf16rne(ex[7]*inv) << 16);
        *(uint4*)(pbf + (size_t)row * 512 + c0) = st;       // coalesced 1 KB/wave
        if (lane == 0) ls[row] = ex[0] * inv;               // p0 (col 0 always < tl)
    } else {
        if (lane == 0) ls[row] = __logf(s);
    }
}

// ---------------- Pass A2 (slow path only): per-sample sum of ln-denominators ----------------
__global__ __launch_bounds__(256) void k_lsum(const float* __restrict__ ls,
                                              const int* __restrict__ mel_lens,
                                              float* __restrict__ lsums) {
    const int b  = blockIdx.x;
    const int ml = mel_lens[b];
    float s = 0.f;
    for (int i = threadIdx.x; i < ml; i += 256) s += ls[(size_t)b * T_ + i];
#pragma unroll
    for (int off = 32; off; off >>= 1) s += __shfl_xor(s, off);
    __shared__ float ws[4];
    if ((threadIdx.x & 63) == 0) ws[threadIdx.x >> 6] = s;
    __syncthreads();
    if (threadIdx.x == 0) lsums[b] = (ws[0] + ws[1]) + (ws[2] + ws[3]);
}

// ---------------- packed recursion pieces ----------------
// Slot j holds CTC pairs (lane*8+j, lane*8+4+j) as float2 (X=low, Y=high).
__device__ __forceinline__ void renorm_exp_pk(f32x2* __restrict__ Ae,
                                              f32x2* __restrict__ Ao, int& exacc) {
    const f32x2 m0 = __builtin_elementwise_max(__builtin_elementwise_max(Ae[0], Ao[0]),
                                               __builtin_elementwise_max(Ae[1], Ao[1]));
    const f32x2 m1 = __builtin_elementwise_max(__builtin_elementwise_max(Ae[2], Ao[2]),
                                               __builtin_elementwise_max(Ae[3], Ao[3]));
    const f32x2 m2 = __builtin_elementwise_max(m0, m1);
    float m = fmaxf(m2.x, m2.y);
    m = fmaxf(m, dppmov<0x111>(m));   // row_shr:1
    m = fmaxf(m, dppmov<0x112>(m));   // row_shr:2
    m = fmaxf(m, dppmov<0x114>(m));   // row_shr:4
    m = fmaxf(m, dppmov<0x118>(m));   // row_shr:8
    m = fmaxf(m, dppmov<0x142>(m));   // row_bcast:15
    m = fmaxf(m, dppmov<0x143>(m));   // row_bcast:31 -> lane 63 holds wave max
    const int wmb = __builtin_amdgcn_readlane(__float_as_int(m), 63);
    int ex = ((wmb >> 23) & 0xFF) - 127;
    if (ex < -60) ex = -60;                 // guard vs denorm/zero max
    exacc += ex - 66;
    const float scale = __int_as_float((unsigned)(193 - ex) << 23);  // 2^(66-ex), exact
    const f32x2 sc = {scale, scale};
#pragma unroll
    for (int j = 0; j < 4; ++j) { Ae[j] *= sc; Ao[j] *= sc; }
}

__device__ __forceinline__ void update_pk(const float p0,
                                          const f32x2 pk0, const f32x2 pk1,
                                          const f32x2 pk2, const f32x2 pk3,
                                          f32x2* __restrict__ Ae, f32x2* __restrict__ Ao) {
    const float bnd = dppmov<0x138>(Ao[3].y);   // wave_shr:1; lane0 reads 0
    f32x2 prev0; prev0.x = bnd; prev0.y = Ao[3].x;
    const f32x2 E0 = Ae[0] + prev0;
    const f32x2 E1 = Ae[1] + Ao[0];
    const f32x2 E2 = Ae[2] + Ao[1];
    const f32x2 E3 = Ae[3] + Ao[2];
    const f32x2 T0 = Ao[0] + E0;
    const f32x2 T1 = Ao[1] + E1;
    const f32x2 T2 = Ao[2] + E2;
    const f32x2 T3 = Ao[3] + E3;
    const f32x2 vp0 = {p0, p0};
    Ae[0] = E0 * vp0; Ae[1] = E1 * vp0; Ae[2] = E2 * vp0; Ae[3] = E3 * vp0;
    Ao[0] = T0 * pk0; Ao[1] = T1 * pk1; Ao[2] = T2 * pk2; Ao[3] = T3 * pk3;
}

// ---------------- Pass B (fast): bf16 probs, block-batched p0, 32-bit addressing ----------------
__global__ __launch_bounds__(64) void k_ctc_bf16(const unsigned short* __restrict__ pbf,
                                                 const int* __restrict__ text_lens,
                                                 const int* __restrict__ mel_lens,
                                                 const float* __restrict__ p0arr,
                                                 float* __restrict__ losses) {
    const int b    = blockIdx.x;
    const int lane = threadIdx.x;
    const int tl   = text_lens[b];
    const int ml   = mel_lens[b];
    const char* __restrict__ base = (const char*)(pbf + (size_t)b * T_ * 512); // 1024 B/row
    const float* __restrict__ p0b = p0arr + (size_t)b * T_;
    const unsigned laneoff = (unsigned)lane * 16;

    // 16-deep rotating register ring; prologue loads rows 1..16 into slots 0..15.
    uint4 raw[16];
#pragma unroll
    for (int s = 0; s < 16; ++s)
        raw[s] = *(const uint4*)(base + ((unsigned)(s + 1) << 10) + laneoff);

    f32x2 Ae[4], Ao[4];
#pragma unroll
    for (int j = 0; j < 4; ++j) { Ae[j] = (f32x2){0.f, 0.f}; Ao[j] = (f32x2){0.f, 0.f}; }
    {   // alpha0[0] = alpha0[1] = p(t=0, class 0), pre-scaled by 2^66; pair 0 = slot0.x
        const float p00 = p0b[0] * 0x1p66f;
        if (lane == 0) { Ae[0].x = p00; Ao[0].x = p00; }
    }
    int exacc = -66;                  // lognorm = exacc * ln2 at the end

    // p0 block registers (SGPR): current block's 16 values; prefetched one block ahead.
    f32x8v p0lo = ((const f32x8u*)(p0b + 1))->v;   // p0[1..8]
    f32x8v p0hi = ((const f32x8u*)(p0b + 9))->v;   // p0[9..16]
#define P0AT(S) (((S) < 8) ? p0lo[(S) & 7] : p0hi[(S) & 7])

#define CVT8(SLOT, P)  { const uint4 w = raw[SLOT];                                   \
        P[0].x=__uint_as_float(w.x<<16); P[0].y=__uint_as_float(w.x&0xFFFF0000u);     \
        P[1].x=__uint_as_float(w.y<<16); P[1].y=__uint_as_float(w.y&0xFFFF0000u);     \
        P[2].x=__uint_as_float(w.z<<16); P[2].y=__uint_as_float(w.z&0xFFFF0000u);     \
        P[3].x=__uint_as_float(w.w<<16); P[3].y=__uint_as_float(w.w&0xFFFF0000u); }

    f32x2 pA[4], pB[4];
    CVT8(0, pA)                       // row 1 (= first consumed row)

    // Step S (t = tb+S): reload slot S with row t+16 (32-bit block-uniform byte
    // addressing -> saddr+imm), CVT slot S+1 for next step, packed update.
#define STEP_MAIN(S, PIN, POUT, CLAMPED)                                       \
    { unsigned tr = (unsigned)(tb + (S) + 16);                                 \
      if (CLAMPED) { if ((int)tr > ml - 1) tr = (unsigned)(ml - 1); }          \
      raw[S] = *(const uint4*)(base + (tr << 10) + laneoff); }                 \
    CVT8(((S) + 1) & 15, POUT)                                                 \
    update_pk(P0AT(S), PIN[0], PIN[1], PIN[2], PIN[3], Ae, Ao);                \
    if (((S) & 7) == 7) renorm_exp_pk(Ae, Ao, exacc);

    // One 16-step block: prefetch next block's p0 (scalar, ~2000 cy ahead), 16 steps,
    // then swap in the prefetched p0. Transition block's prefetch may read up to
    // p0b[tb+31] (> ml-1 but within the ws allocation; unconsumed).
#define BLOCK16(CLAMPED)                                                       \
    { const f32x8v nlo = ((const f32x8u*)(p0b + tb + 16))->v;                  \
      const f32x8v nhi = ((const f32x8u*)(p0b + tb + 24))->v;                  \
      STEP_MAIN(0,  pA, pB, CLAMPED)                                           \
      STEP_MAIN(1,  pB, pA, CLAMPED)                                           \
      STEP_MAIN(2,  pA, pB, CLAMPED)                                           \
      STEP_MAIN(3,  pB, pA, CLAMPED)                                           \
      STEP_MAIN(4,  pA, pB, CLAMPED)                                           \
      STEP_MAIN(5,  pB, pA, CLAMPED)                                           \
      STEP_MAIN(6,  pA, pB, CLAMPED)                                           \
      STEP_MAIN(7,  pB, pA, CLAMPED)                                           \
      STEP_MAIN(8,  pA, pB, CLAMPED)                                           \
      STEP_MAIN(9,  pB, pA, CLAMPED)                                           \
      STEP_MAIN(10, pA, pB, CLAMPED)                                           \
      STEP_MAIN(11, pB, pA, CLAMPED)                                           \
      STEP_MAIN(12, pA, pB, CLAMPED)                                           \
      STEP_MAIN(13, pB, pA, CLAMPED)                                           \
      STEP_MAIN(14, pA, pB, CLAMPED)                                           \
      STEP_MAIN(15, pB, pA, CLAMPED)                                           \
      p0lo = nlo; p0hi = nhi; }

    int tb = 1;
    for (; tb + 32 <= ml; tb += 16) {       // steady: reloads never clamp
        BLOCK16(0)
    }
    if (tb + 16 <= ml) {                    // one transition block with clamped reloads
        BLOCK16(1)
        tb += 16;
    }

    // tail: steps tb..ml-1 (<16); rows resident in ring, p0 in p0lo/p0hi (prefetched
    // by the previous block). No renorm (p<=1: shrink-only drift stays in range).
#define STEP_TAIL(S, PIN, POUT)                                                \
    if (tb + (S) < ml) {                                                       \
        CVT8(((S) + 1) & 15, POUT)                                             \
        update_pk(P0AT(S), PIN[0], PIN[1], PIN[2], PIN[3], Ae, Ao);            \
    }
    STEP_TAIL(0,  pA, pB)
    STEP_TAIL(1,  pB, pA)
    STEP_TAIL(2,  pA, pB)
    STEP_TAIL(3,  pB, pA)
    STEP_TAIL(4,  pA, pB)
    STEP_TAIL(5,  pB, pA)
    STEP_TAIL(6,  pA, pB)
    STEP_TAIL(7,  pB, pA)
    STEP_TAIL(8,  pA, pB)
    STEP_TAIL(9,  pB, pA)
    STEP_TAIL(10, pA, pB)
    STEP_TAIL(11, pB, pA)
    STEP_TAIL(12, pA, pB)
    STEP_TAIL(13, pB, pA)
    STEP_TAIL(14, pA, pB)
    STEP_TAIL(15, pB, pA)
#undef STEP_TAIL
#undef BLOCK16
#undef STEP_MAIN
#undef CVT8
#undef P0AT

    // epilogue: probs normalized -> ll = ln(contrib) + exacc*ln2
    float contrib = 0.f;
#pragma unroll
    for (int j = 0; j < 4; ++j) {
        const int kx = lane * 8 + j;
        const int ky = kx + 4;
        if (kx == tl)     contrib += Ae[j].x;
        if (kx == tl - 1) contrib += Ao[j].x;
        if (ky == tl)     contrib += Ae[j].y;
        if (ky == tl - 1) contrib += Ao[j].y;
    }
#pragma unroll
    for (int off = 32; off; off >>= 1) contrib += __shfl_xor(contrib, off);
    if (lane == 0) {
        float loss = 0.f;
        if (contrib > 0.f) {
            const float ll = __logf(contrib) + (float)exacc * 0.69314718056f;
            loss = -ll / (float)tl;
        }
        losses[b] = loss;
    }
}

// ---------------- Pass B (slow fallback, proven R4): direct logit loads ----------------
template <int PP>
__device__ __forceinline__ void step_update(const float p0, const float* __restrict__ p,
                                            float* __restrict__ aeven, float* __restrict__ aodd) {
    float prev = dppmov<0x138>(aodd[PP - 1]);
#pragma unroll
    for (int j = 0; j < PP; ++j) {
        const float oldodd = aodd[j];
        const float e = aeven[j] + prev;
        aeven[j] = e * p0;
        aodd[j]  = (oldodd + e) * p[j];
        prev = oldodd;
    }
}

template <int PP>
__device__ __forceinline__ void renorm(float* __restrict__ aeven, float* __restrict__ aodd,
                                       float& lognorm) {
    float m = 0.f;
#pragma unroll
    for (int j = 0; j < PP; ++j) m = fmaxf(m, fmaxf(aeven[j], aodd[j]));
    m = fmaxf(m, dppmov<0x111>(m));
    m = fmaxf(m, dppmov<0x112>(m));
    m = fmaxf(m, dppmov<0x114>(m));
    m = fmaxf(m, dppmov<0x118>(m));
    m = fmaxf(m, dppmov<0x142>(m));
    m = fmaxf(m, dppmov<0x143>(m));
    const float wm  = __int_as_float(__builtin_amdgcn_readlane(__float_as_int(m), 63));
    const float inv = 1.0f / wm;
    lognorm += __logf(wm) - LOGM0f;
#pragma unroll
    for (int j = 0; j < PP; ++j) {
        aeven[j] = (aeven[j] * inv) * M0f;
        aodd[j]  = (aodd[j]  * inv) * M0f;
    }
}

template <int PP>
__device__ __forceinline__ void ctc_run_slow(const float* __restrict__ Lb, float lsum,
                                             int tl, int ml, float* __restrict__ loss_out) {
    const int lane = threadIdx.x;
    const int base = lane * PP;
    int   idx[PP];
    float mask[PP];
#pragma unroll
    for (int j = 0; j < PP; ++j) {
        const int k = base + j;
        idx[j]  = (k < C_) ? k : (C_ - 1);
        mask[j] = (k < tl) ? 1.f : 0.f;
    }
    float raw[8][PP];
#pragma unroll
    for (int s = 0; s < 8; ++s) {
        const float* __restrict__ rowp = Lb + (size_t)(s + 1) * C_;
#pragma unroll
        for (int j = 0; j < PP; ++j) raw[s][j] = rowp[idx[j]];
    }
    float aeven[PP], aodd[PP];
#pragma unroll
    for (int j = 0; j < PP; ++j) { aeven[j] = 0.f; aodd[j] = 0.f; }
    {
        const float a00 = __expf(Lb[0]) * M0f;
        if (lane == 0) { aeven[0] = a00; aodd[0] = a00; }
    }
    float lognorm = -LOGM0f;
    int tb = 1;
    for (; tb + 8 <= ml; tb += 8) {
#pragma unroll
        for (int s = 0; s < 8; ++s) {
            const int tt = tb + s;
            const float p0 = __expf(bcast0(raw[s][0]));
            float p[PP];
#pragma unroll
            for (int j = 0; j < PP; ++j) p[j] = __expf(raw[s][j]) * mask[j];
            { int tr = tt + 8; if (tr > ml - 1) tr = ml - 1;
              const float* __restrict__ rowp = Lb + (size_t)tr * C_;
#pragma unroll
              for (int j = 0; j < PP; ++j) raw[s][j] = rowp[idx[j]]; }
            step_update<PP>(p0, p, aeven, aodd);
            if (s == 7) renorm<PP>(aeven, aodd, lognorm);
        }
    }
#pragma unroll
    for (int s = 0; s < 8; ++s) {
        const int tt = tb + s;
        if (tt < ml) {
            const float p0 = __expf(bcast0(raw[s][0]));
            float p[PP];
#pragma unroll
            for (int j = 0; j < PP; ++j) p[j] = __expf(raw[s][j]) * mask[j];
            step_update<PP>(p0, p, aeven, aodd);
            if (s == 7) renorm<PP>(aeven, aodd, lognorm);
        }
    }
    float contrib = 0.f;
#pragma unroll
    for (int j = 0; j < PP; ++j) {
        const int k = base + j;
        if (k == tl)     contrib += aeven[j];
        if (k == tl - 1) contrib += aodd[j];
    }
#pragma unroll
    for (int off = 32; off; off >>= 1) contrib += __shfl_xor(contrib, off);
    if (lane == 0) {
        float loss = 0.f;
        if (contrib > 0.f) {
            const float ll = __logf(contrib) + lognorm - lsum;   // raw domain: -lsum needed
            loss = -ll / (float)tl;
        }
        *loss_out = loss;
    }
}

__global__ __launch_bounds__(64) void k_ctc_slow(const float* __restrict__ logits,
                                                 const int* __restrict__ text_lens,
                                                 const int* __restrict__ mel_lens,
                                                 const float* __restrict__ lsums,
                                                 float* __restrict__ losses) {
    const int b  = blockIdx.x;
    const int tl = text_lens[b];
    const int ml = mel_lens[b];
    const float lsum = lsums[b];
    const float* Lb = logits + (size_t)b * T_ * C_;
    float* lo = losses + b;
    const int PP = (tl + 1 + 63) >> 6;
    switch (PP) {
        case 1: ctc_run_slow<1>(Lb, lsum, tl, ml, lo); break;
        case 2: ctc_run_slow<2>(Lb, lsum, tl, ml, lo); break;
        case 3: ctc_run_slow<3>(Lb, lsum, tl, ml, lo); break;
        case 4: ctc_run_slow<4>(Lb, lsum, tl, ml, lo); break;
        case 5: ctc_run_slow<5>(Lb, lsum, tl, ml, lo); break;
        case 6: ctc_run_slow<6>(Lb, lsum, tl, ml, lo); break;
        default: ctc_run_slow<7>(Lb, lsum, tl, ml, lo); break;
    }
}

// ---------------- Pass C: deterministic mean ----------------
__global__ __launch_bounds__(64) void k_final(const float* __restrict__ losses,
                                              float* __restrict__ out) {
    const int lane = threadIdx.x;
    float v = (lane < B_) ? losses[lane] : 0.f;
#pragma unroll
    for (int off = 32; off; off >>= 1) v += __shfl_xor(v, off);
    if (lane == 0) out[0] = v * (1.0f / B_);
}

extern "C" void kernel_launch(void* const* d_in, const int* in_sizes, int n_in,
                              void* d_out, int out_size, void* d_ws, size_t ws_size,
                              hipStream_t stream) {
    const float* logits    = (const float*)d_in[0];   // [B,1,T,C] fp32
    const int*   text_lens = (const int*)d_in[1];     // [B] int32
    const int*   mel_lens  = (const int*)d_in[2];     // [B] int32
    float* out = (float*)d_out;

    const size_t PBF_BYTES  = (size_t)B_ * T_ * 512 * 2;          // 65,536,000
    const size_t tail_bytes = (size_t)B_ * T_ * 4 + 2 * B_ * 4 + 64;

    if (ws_size >= PBF_BYTES + tail_bytes) {
        unsigned short* pbf = (unsigned short*)d_ws;
        float* ls     = (float*)((char*)d_ws + PBF_BYTES);    // p0[t] per row
        float* lsums  = ls + (size_t)B_ * T_;
        float* losses = lsums + B_;
        k_prob<<<B_ * T_ / 4, 256, 0, stream>>>(logits, text_lens, pbf, ls);
        k_ctc_bf16<<<B_, 64, 0, stream>>>(pbf, text_lens, mel_lens, ls, losses);
        k_final<<<1, 64, 0, stream>>>(losses, out);
    } else {
        float* ls     = (float*)d_ws;
        float* lsums  = ls + (size_t)B_ * T_;
        float* losses = lsums + B_;
        k_prob<<<B_ * T_ / 4, 256, 0, stream>>>(logits, text_lens, nullptr, ls);
        k_lsum<<<B_, 256, 0, stream>>>(ls, mel_lens, lsums);
        k_ctc_slow<<<B_, 64, 0, stream>>>(logits, text_lens, mel_lens, lsums, losses);
        k_final<<<1, 64, 0, stream>>>(losses, out);
    }
}

// Round 16
// 164.216 us; speedup vs baseline: 1.3433x; 1.0978x over previous
//
#include <hip/hip_runtime.h>

// ForwardSumLossWithBlank: CTC forward (alpha) loss, blank=0, targets=arange(text_len).
// B=32, T=2000 mel frames, C=400 classes. Output: scalar mean loss (fp32).
//
// FAST path (~66 MB ws): bf16 normalized probs (L2-resident), TWO waves per sample:
//   wave0 owns CTC pairs [0,256), wave1 owns [256,512). One-way producer->consumer:
//   wave0 writes (pair-255 odd state, its frame exponent) into a NEVER-WRAPPING
//   2048-entry LDS ring (one entry per time step, written once -> no backpressure);
//   wave1 injects ring[t-1] at step t via exact ldexp cross-frame scaling:
//   true = stored * 2^exacc  =>  inj = ldexpf(bnd, ey - exacc)   [R15 bug: sign was
//   flipped -> Inf/NaN in wave1 -> tl>=257 losses zeroed -> absmax 5.5. Fixed.]
//   Sync = monotone LDS flag, published per 16-block by wave0 (fence+store), spin-
//   checked per block by wave1; sentinel after wave0's tail -> deadlock-free.
//   Independent exponent renorm frames per wave; wave1 slaves its frame to the
//   producer's while its half is all-zero so the seed cannot flush. Epilogue:
//   logaddexp combine of the two frames.
// SLOW path: R4 kernels (raw exp(logits), -lsum epilogue).

static constexpr int B_ = 32;
static constexpr int T_ = 2000;
static constexpr int C_ = 400;
static constexpr float M0f    = 1e20f;
static constexpr float LOGM0f = 46.05170186f;   // ln(1e20) (fallback path)

typedef float f32x2 __attribute__((ext_vector_type(2)));
typedef float f32x8v __attribute__((ext_vector_type(8)));
struct __attribute__((packed, aligned(4))) f32x8u { f32x8v v; };

template <int CTRL>
__device__ __forceinline__ float dppmov(float v) {
    // mov_dpp, bound_ctrl=1: invalid-source lanes read 0 (safe: alphas >= 0).
    return __int_as_float(__builtin_amdgcn_update_dpp(
        0, __float_as_int(v), CTRL, 0xF, 0xF, true));
}

__device__ __forceinline__ float bcast0(float v) {
    return __int_as_float(__builtin_amdgcn_readfirstlane(__float_as_int(v)));
}

__device__ __forceinline__ unsigned bf16rne(float f) {
    unsigned u = __float_as_uint(f);
    u += 0x7FFFu + ((u >> 16) & 1u);
    return u >> 16;
}

// ---------------- Pass A: masked normalized probs (bf16, padded 512) ----------------
// fast (pbf!=null): split-pair packing (c, c+2) per dword; ls[row] = p0 (f32).
// slow (pbf==null): ls[row] = ln(sum exp).
__global__ __launch_bounds__(256) void k_prob(const float* __restrict__ logits,
                                              const int* __restrict__ text_lens,
                                              unsigned short* __restrict__ pbf,
                                              float* __restrict__ ls) {
    const int lane = threadIdx.x & 63;
    const int row  = blockIdx.x * 4 + (threadIdx.x >> 6);   // grid = B*T/4 exactly
    const int b    = row / T_;
    const int tl   = text_lens[b];
    const float* __restrict__ r = logits + (size_t)row * C_;

    const int c0 = lane * 8;
    float v[8];
    if (c0 < C_) {           // row is 1600 B, 16B-aligned; lane<50 reads [c0, c0+8)
        const float4 a = *(const float4*)(r + c0);
        const float4 c = *(const float4*)(r + c0 + 4);
        v[0]=a.x; v[1]=a.y; v[2]=a.z; v[3]=a.w; v[4]=c.x; v[5]=c.y; v[6]=c.z; v[7]=c.w;
    } else {
#pragma unroll
        for (int e = 0; e < 8; ++e) v[e] = 0.f;             // masked below anyway
    }
    float ex[8]; float s = 0.f;
#pragma unroll
    for (int e = 0; e < 8; ++e) {
        const int c = c0 + e;
        const float t = (c < tl) ? __expf(v[e]) : 0.f;      // tl <= 400 -> cols>=400 masked
        ex[e] = t; s += t;
    }
#pragma unroll
    for (int off = 32; off; off >>= 1) s += __shfl_xor(s, off);

    if (pbf) {
        const float inv = 1.0f / s;
        // dword d = (bf16[col 2d'], bf16[col 2d'+2]) per the 2-wave consumer layout:
        // consumer (W,l) slot j = pairs (256W+4l+j, +2).
        uint4 st;
        st.x = bf16rne(ex[0]*inv) | (bf16rne(ex[2]*inv) << 16);
        st.y = bf16rne(ex[1]*inv) | (bf16rne(ex[3]*inv) << 16);
        st.z = bf16rne(ex[4]*inv) | (bf16rne(ex[6]*inv) << 16);
        st.w = bf16rne(ex[5]*inv) | (bf16rne(ex[7]*inv) << 16);
        *(uint4*)(pbf + (size_t)row * 512 + c0) = st;       // coalesced 1 KB/wave
        if (lane == 0) ls[row] = ex[0] * inv;               // p0 (col 0 always < tl)
    } else {
        if (lane == 0) ls[row] = __logf(s);
    }
}

// ---------------- Pass A2 (slow path only): per-sample sum of ln-denominators ----------------
__global__ __launch_bounds__(256) void k_lsum(const float* __restrict__ ls,
                                              const int* __restrict__ mel_lens,
                                              float* __restrict__ lsums) {
    const int b  = blockIdx.x;
    const int ml = mel_lens[b];
    float s = 0.f;
    for (int i = threadIdx.x; i < ml; i += 256) s += ls[(size_t)b * T_ + i];
#pragma unroll
    for (int off = 32; off; off >>= 1) s += __shfl_xor(s, off);
    __shared__ float ws[4];
    if ((threadIdx.x & 63) == 0) ws[threadIdx.x >> 6] = s;
    __syncthreads();
    if (threadIdx.x == 0) lsums[b] = (ws[0] + ws[1]) + (ws[2] + ws[3]);
}

// ---------------- 2-wave packed recursion pieces ----------------
// Wave W lane l: slot j (j=0,1) = CTC pairs (q0+j, q0+j+2), q0 = 256W + 4l.
// prev(slot0) = (dpp(Ao[1].y) [+inject W=1 lane0], Ao[1].x); prev(slot1) = Ao[0].
template <int W>
__device__ __forceinline__ void update_pk2(const float p0, const f32x2 pk0, const f32x2 pk1,
                                           f32x2* __restrict__ Ae, f32x2* __restrict__ Ao,
                                           const float inj, const float mask0) {
    float bx = dppmov<0x138>(Ao[1].y);   // wave_shr:1; lane0 reads 0
    if constexpr (W == 1) bx = fmaf(inj, mask0, bx);
    f32x2 prev0; prev0.x = bx; prev0.y = Ao[1].x;
    const f32x2 E0 = Ae[0] + prev0;
    const f32x2 E1 = Ae[1] + Ao[0];
    const f32x2 T0 = Ao[0] + E0;
    const f32x2 T1 = Ao[1] + E1;
    const f32x2 vp0 = {p0, p0};
    Ae[0] = E0 * vp0; Ae[1] = E1 * vp0;
    Ao[0] = T0 * pk0; Ao[1] = T1 * pk1;
}

// Per-wave exponent renorm (own frame). W=1: while half is all-zero, slave the frame
// to the producer's latest exponent (exl) so the incoming seed cannot flush.
template <int W>
__device__ __forceinline__ void renorm2(f32x2* __restrict__ Ae, f32x2* __restrict__ Ao,
                                        int& exacc, const int exl) {
    const f32x2 m2 = __builtin_elementwise_max(__builtin_elementwise_max(Ae[0], Ao[0]),
                                               __builtin_elementwise_max(Ae[1], Ao[1]));
    float m = fmaxf(m2.x, m2.y);
    m = fmaxf(m, dppmov<0x111>(m));   // row_shr:1
    m = fmaxf(m, dppmov<0x112>(m));   // row_shr:2
    m = fmaxf(m, dppmov<0x114>(m));   // row_shr:4
    m = fmaxf(m, dppmov<0x118>(m));   // row_shr:8
    m = fmaxf(m, dppmov<0x142>(m));   // row_bcast:15
    m = fmaxf(m, dppmov<0x143>(m));   // row_bcast:31 -> lane 63 holds wave max
    const int wmb = __builtin_amdgcn_readlane(__float_as_int(m), 63);
    if constexpr (W == 1) {
        if (wmb == 0) { exacc = __builtin_amdgcn_readfirstlane(exl); return; }
    }
    int ex = ((wmb >> 23) & 0xFF) - 127;
    if (ex < -60) ex = -60;                 // guard vs denorm/zero max
    exacc += ex - 66;
    const float scale = __int_as_float((unsigned)(193 - ex) << 23);  // 2^(66-ex), exact
    const f32x2 sc = {scale, scale};
    Ae[0] *= sc; Ae[1] *= sc; Ao[0] *= sc; Ao[1] *= sc;
}

#define CVT4(SLOT, P)  { const uint2 wv = raw[SLOT];                                  \
        P[0].x=__uint_as_float(wv.x<<16); P[0].y=__uint_as_float(wv.x&0xFFFF0000u);   \
        P[1].x=__uint_as_float(wv.y<<16); P[1].y=__uint_as_float(wv.y&0xFFFF0000u); }

template <int W>
__device__ void ctc_half(const char* __restrict__ baseW, const float* __restrict__ p0b,
                         int tl, int ml, uint2* __restrict__ ring_, volatile int* vflag,
                         float* __restrict__ cs, int* __restrict__ es, int lane) {
    const unsigned laneoff = (unsigned)lane * 8;

    // 16-deep rotating prob ring; prologue loads rows 1..16 into slots 0..15.
    uint2 raw[16];
#pragma unroll
    for (int s = 0; s < 16; ++s)
        raw[s] = *(const uint2*)(baseW + ((unsigned)(s + 1) << 10) + laneoff);

    f32x2 Ae[2], Ao[2];
    Ae[0] = Ae[1] = Ao[0] = Ao[1] = (f32x2){0.f, 0.f};
    if (W == 0 && lane == 0) {       // alpha0: pair 0 even/odd = p(t=0, class 0) * 2^66
        const float p00 = p0b[0] * 0x1p66f;
        Ae[0].x = p00; Ao[0].x = p00;
    }
    int exacc = -66;
    int exl   = -66;
    const float mask0 = (W == 1 && lane == 0) ? 1.f : 0.f;

    f32x8v p0lo = ((const f32x8u*)(p0b + 1))->v;   // p0[1..8]
    f32x8v p0hi = ((const f32x8u*)(p0b + 9))->v;   // p0[9..16]
#define P0AT(S) (((S) < 8) ? p0lo[(S) & 7] : p0hi[(S) & 7])

    f32x2 pA[2], pB[2];
    uint2 erA = {0u, 0u}, erB = {0u, 0u};
    CVT4(0, pA)

    int tb = 1;
    if constexpr (W == 1) {          // initial sync + boundary prefetch (entries 0,1)
        while (*vflag < 17) __builtin_amdgcn_s_sleep(1);
        __threadfence_block();
        erB = ring_[0];              // consumed at t=1 (parity 1)
        erA = ring_[1];              // consumed at t=2 (parity 0)
    }

    // Step S (t = tb+S): reload prob slot S with row t+16; CVT slot S+1; W=1: consume
    // ring[t-1] (prefetched 2 back), exact ldexp cross-frame inject (ey - exacc),
    // prefetch ring[t+1]; update; W=0: write ring[t] = (new pair-255 odd, exacc);
    // renorm each 8th step.
#define STEP2(S, PIN, POUT, CLAMPED)                                            \
    {                                                                           \
        { unsigned tr = (unsigned)(tb + (S) + 16);                              \
          if (CLAMPED) { if ((int)tr > ml - 1) tr = (unsigned)(ml - 1); }       \
          raw[S] = *(const uint2*)(baseW + (tr << 10) + laneoff); }             \
        CVT4(((S) + 1) & 15, POUT)                                              \
        float inj = 0.f;                                                        \
        if constexpr (W == 1) {                                                 \
            constexpr int Pr = ((S) ^ 1) & 1;                                   \
            const uint2 e = Pr ? erB : erA;                                     \
            inj = ldexpf(__uint_as_float(e.x), (int)e.y - exacc);               \
            exl = (int)e.y;                                                     \
            (Pr ? erB : erA) = ring_[tb + (S) + 1];                             \
        }                                                                       \
        update_pk2<W>(P0AT(S), PIN[0], PIN[1], Ae, Ao, inj, mask0);             \
        if constexpr (W == 0) {                                                 \
            uint2 pkv; pkv.x = __float_as_uint(Ao[1].y); pkv.y = (unsigned)exacc; \
            ring_[(lane == 63) ? (tb + (S)) : 2040] = pkv;                      \
        }                                                                       \
        if (((S) & 7) == 7) renorm2<W>(Ae, Ao, exacc, exl);                     \
    }

#define BLOCK16(CLAMPED)                                                        \
    { const f32x8v nlo = ((const f32x8u*)(p0b + tb + 16))->v;                   \
      const f32x8v nhi = ((const f32x8u*)(p0b + tb + 24))->v;                   \
      if constexpr (W == 1) {                                                   \
          while (*vflag < tb + 16) __builtin_amdgcn_s_sleep(1);                 \
          __threadfence_block();                                                \
      }                                                                         \
      STEP2(0,  pA, pB, CLAMPED)  STEP2(1,  pB, pA, CLAMPED)                    \
      STEP2(2,  pA, pB, CLAMPED)  STEP2(3,  pB, pA, CLAMPED)                    \
      STEP2(4,  pA, pB, CLAMPED)  STEP2(5,  pB, pA, CLAMPED)                    \
      STEP2(6,  pA, pB, CLAMPED)  STEP2(7,  pB, pA, CLAMPED)                    \
      STEP2(8,  pA, pB, CLAMPED)  STEP2(9,  pB, pA, CLAMPED)                    \
      STEP2(10, pA, pB, CLAMPED)  STEP2(11, pB, pA, CLAMPED)                    \
      STEP2(12, pA, pB, CLAMPED)  STEP2(13, pB, pA, CLAMPED)                    \
      STEP2(14, pA, pB, CLAMPED)  STEP2(15, pB, pA, CLAMPED)                    \
      if constexpr (W == 0) {                                                   \
          __threadfence_block();                                                \
          if (lane == 0) *vflag = tb + 15;                                      \
      }                                                                         \
      p0lo = nlo; p0hi = nhi; }

    for (; tb + 32 <= ml; tb += 16) {       // steady: prob reloads never clamp
        BLOCK16(0)
    }
    if (tb + 16 <= ml) {                    // one transition block with clamps
        BLOCK16(1)
        tb += 16;
    }

    if constexpr (W == 1) {                  // wait for producer fully done (tiny tail)
        while (*vflag < (1 << 29)) __builtin_amdgcn_s_sleep(1);
        __threadfence_block();
    }

    // tail: steps tb..ml-1 (<16); prob rows resident; no renorm (<=15 shrink-only steps).
#define STEP_TAIL2(S, PIN, POUT)                                                \
    if (tb + (S) < ml) {                                                        \
        CVT4(((S) + 1) & 15, POUT)                                              \
        float inj = 0.f;                                                        \
        if constexpr (W == 1) {                                                 \
            constexpr int Pr = ((S) ^ 1) & 1;                                   \
            const uint2 e = Pr ? erB : erA;                                     \
            inj = ldexpf(__uint_as_float(e.x), (int)e.y - exacc);               \
            (Pr ? erB : erA) = ring_[tb + (S) + 1];                             \
        }                                                                       \
        update_pk2<W>(P0AT(S), PIN[0], PIN[1], Ae, Ao, inj, mask0);             \
        if constexpr (W == 0) {                                                 \
            uint2 pkv; pkv.x = __float_as_uint(Ao[1].y); pkv.y = (unsigned)exacc; \
            ring_[(lane == 63) ? (tb + (S)) : 2040] = pkv;                      \
        }                                                                       \
    }
    STEP_TAIL2(0,  pA, pB)  STEP_TAIL2(1,  pB, pA)
    STEP_TAIL2(2,  pA, pB)  STEP_TAIL2(3,  pB, pA)
    STEP_TAIL2(4,  pA, pB)  STEP_TAIL2(5,  pB, pA)
    STEP_TAIL2(6,  pA, pB)  STEP_TAIL2(7,  pB, pA)
    STEP_TAIL2(8,  pA, pB)  STEP_TAIL2(9,  pB, pA)
    STEP_TAIL2(10, pA, pB)  STEP_TAIL2(11, pB, pA)
    STEP_TAIL2(12, pA, pB)  STEP_TAIL2(13, pB, pA)
    STEP_TAIL2(14, pA, pB)  STEP_TAIL2(15, pB, pA)
#undef STEP_TAIL2
#undef BLOCK16
#undef STEP2
#undef P0AT

    if constexpr (W == 0) {                  // release wave1's tail
        __threadfence_block();
        if (lane == 0) *vflag = (1 << 30);
    }

    // partial contrib in this wave's frame
    float contrib = 0.f;
    const int q0 = 256 * W + lane * 4;
    if (q0     == tl)     contrib += Ae[0].x;
    if (q0     == tl - 1) contrib += Ao[0].x;
    if (q0 + 2 == tl)     contrib += Ae[0].y;
    if (q0 + 2 == tl - 1) contrib += Ao[0].y;
    if (q0 + 1 == tl)     contrib += Ae[1].x;
    if (q0 + 1 == tl - 1) contrib += Ao[1].x;
    if (q0 + 3 == tl)     contrib += Ae[1].y;
    if (q0 + 3 == tl - 1) contrib += Ao[1].y;
#pragma unroll
    for (int off = 32; off; off >>= 1) contrib += __shfl_xor(contrib, off);
    if (lane == 0) { cs[W] = contrib; es[W] = exacc; }
}

__global__ __launch_bounds__(128) void k_ctc2(const unsigned short* __restrict__ pbf,
                                              const int* __restrict__ text_lens,
                                              const int* __restrict__ mel_lens,
                                              const float* __restrict__ p0arr,
                                              float* __restrict__ losses) {
    __shared__ uint2 ring_[2048];   // 16 KB: one entry per time step (never wraps)
    __shared__ int   flag_;
    __shared__ float cs[2];
    __shared__ int   es[2];
    const int b    = blockIdx.x;
    const int tid  = threadIdx.x;
    const int w    = tid >> 6;
    const int lane = tid & 63;
    const int tl   = text_lens[b];
    const int ml   = mel_lens[b];
    if (tid == 0) {
        flag_ = 0;
        ring_[0].x = 0u; ring_[0].y = (unsigned)(-66);   // alpha_0 boundary = 0, frame -66
    }
    __syncthreads();

    const char* baseW = (const char*)(pbf + (size_t)b * T_ * 512) + 512 * w;
    const float* p0b  = p0arr + (size_t)b * T_;
    if (w == 0) ctc_half<0>(baseW, p0b, tl, ml, ring_, &flag_, cs, es, lane);
    else        ctc_half<1>(baseW, p0b, tl, ml, ring_, &flag_, cs, es, lane);
    __syncthreads();

    if (tid == 0) {
        const float c0 = cs[0], c1 = cs[1];
        const bool h0 = c0 > 0.f, h1 = c1 > 0.f;
        float loss = 0.f;
        if (h0 || h1) {
            const float LN2 = 0.69314718056f;
            float ll;
            if (h0 && h1) {
                const float l0 = __logf(c0) + (float)es[0] * LN2;
                const float l1 = __logf(c1) + (float)es[1] * LN2;
                const float M = fmaxf(l0, l1);
                ll = M + __logf(__expf(l0 - M) + __expf(l1 - M));
            } else if (h0) {
                ll = __logf(c0) + (float)es[0] * LN2;
            } else {
                ll = __logf(c1) + (float)es[1] * LN2;
            }
            loss = -ll / (float)tl;
        }
        losses[b] = loss;
    }
}

// ---------------- Pass B (slow fallback, proven R4): direct logit loads ----------------
template <int PP>
__device__ __forceinline__ void step_update(const float p0, const float* __restrict__ p,
                                            float* __restrict__ aeven, float* __restrict__ aodd) {
    float prev = dppmov<0x138>(aodd[PP - 1]);
#pragma unroll
    for (int j = 0; j < PP; ++j) {
        const float oldodd = aodd[j];
        const float e = aeven[j] + prev;
        aeven[j] = e * p0;
        aodd[j]  = (oldodd + e) * p[j];
        prev = oldodd;
    }
}

template <int PP>
__device__ __forceinline__ void renorm(float* __restrict__ aeven, float* __restrict__ aodd,
                                       float& lognorm) {
    float m = 0.f;
#pragma unroll
    for (int j = 0; j < PP; ++j) m = fmaxf(m, fmaxf(aeven[j], aodd[j]));
    m = fmaxf(m, dppmov<0x111>(m));
    m = fmaxf(m, dppmov<0x112>(m));
    m = fmaxf(m, dppmov<0x114>(m));
    m = fmaxf(m, dppmov<0x118>(m));
    m = fmaxf(m, dppmov<0x142>(m));
    m = fmaxf(m, dppmov<0x143>(m));
    const float wm  = __int_as_float(__builtin_amdgcn_readlane(__float_as_int(m), 63));
    const float inv = 1.0f / wm;
    lognorm += __logf(wm) - LOGM0f;
#pragma unroll
    for (int j = 0; j < PP; ++j) {
        aeven[j] = (aeven[j] * inv) * M0f;
        aodd[j]  = (aodd[j]  * inv) * M0f;
    }
}

template <int PP>
__device__ __forceinline__ void ctc_run_slow(const float* __restrict__ Lb, float lsum,
                                             int tl, int ml, float* __restrict__ loss_out) {
    const int lane = threadIdx.x;
    const int base = lane * PP;
    int   idx[PP];
    float mask[PP];
#pragma unroll
    for (int j = 0; j < PP; ++j) {
        const int k = base + j;
        idx[j]  = (k < C_) ? k : (C_ - 1);
        mask[j] = (k < tl) ? 1.f : 0.f;
    }
    float raw[8][PP];
#pragma unroll
    for (int s = 0; s < 8; ++s) {
        const float* __restrict__ rowp = Lb + (size_t)(s + 1) * C_;
#pragma unroll
        for (int j = 0; j < PP; ++j) raw[s][j] = rowp[idx[j]];
    }
    float aeven[PP], aodd[PP];
#pragma unroll
    for (int j = 0; j < PP; ++j) { aeven[j] = 0.f; aodd[j] = 0.f; }
    {
        const float a00 = __expf(Lb[0]) * M0f;
        if (lane == 0) { aeven[0] = a00; aodd[0] = a00; }
    }
    float lognorm = -LOGM0f;
    int tb = 1;
    for (; tb + 8 <= ml; tb += 8) {
#pragma unroll
        for (int s = 0; s < 8; ++s) {
            const int tt = tb + s;
            const float p0 = __expf(bcast0(raw[s][0]));
            float p[PP];
#pragma unroll
            for (int j = 0; j < PP; ++j) p[j] = __expf(raw[s][j]) * mask[j];
            { int tr = tt + 8; if (tr > ml - 1) tr = ml - 1;
              const float* __restrict__ rowp = Lb + (size_t)tr * C_;
#pragma unroll
              for (int j = 0; j < PP; ++j) raw[s][j] = rowp[idx[j]]; }
            step_update<PP>(p0, p, aeven, aodd);
            if (s == 7) renorm<PP>(aeven, aodd, lognorm);
        }
    }
#pragma unroll
    for (int s = 0; s < 8; ++s) {
        const int tt = tb + s;
        if (tt < ml) {
            const float p0 = __expf(bcast0(raw[s][0]));
            float p[PP];
#pragma unroll
            for (int j = 0; j < PP; ++j) p[j] = __expf(raw[s][j]) * mask[j];
            step_update<PP>(p0, p, aeven, aodd);
            if (s == 7) renorm<PP>(aeven, aodd, lognorm);
        }
    }
    float contrib = 0.f;
#pragma unroll
    for (int j = 0; j < PP; ++j) {
        const int k = base + j;
        if (k == tl)     contrib += aeven[j];
        if (k == tl - 1) contrib += aodd[j];
    }
#pragma unroll
    for (int off = 32; off; off >>= 1) contrib += __shfl_xor(contrib, off);
    if (lane == 0) {
        float loss = 0.f;
        if (contrib > 0.f) {
            const float ll = __logf(contrib) + lognorm - lsum;   // raw domain: -lsum needed
            loss = -ll / (float)tl;
        }
        *loss_out = loss;
    }
}

__global__ __launch_bounds__(64) void k_ctc_slow(const float* __restrict__ logits,
                                                 const int* __restrict__ text_lens,
                                                 const int* __restrict__ mel_lens,
                                                 const float* __restrict__ lsums,
                                                 float* __restrict__ losses) {
    const int b  = blockIdx.x;
    const int tl = text_lens[b];
    const int ml = mel_lens[b];
    const float lsum = lsums[b];
    const float* Lb = logits + (size_t)b * T_ * C_;
    float* lo = losses + b;
    const int PP = (tl + 1 + 63) >> 6;
    switch (PP) {
        case 1: ctc_run_slow<1>(Lb, lsum, tl, ml, lo); break;
        case 2: ctc_run_slow<2>(Lb, lsum, tl, ml, lo); break;
        case 3: ctc_run_slow<3>(Lb, lsum, tl, ml, lo); break;
        case 4: ctc_run_slow<4>(Lb, lsum, tl, ml, lo); break;
        case 5: ctc_run_slow<5>(Lb, lsum, tl, ml, lo); break;
        case 6: ctc_run_slow<6>(Lb, lsum, tl, ml, lo); break;
        default: ctc_run_slow<7>(Lb, lsum, tl, ml, lo); break;
    }
}

// ---------------- Pass C: deterministic mean ----------------
__global__ __launch_bounds__(64) void k_final(const float* __restrict__ losses,
                                              float* __restrict__ out) {
    const int lane = threadIdx.x;
    float v = (lane < B_) ? losses[lane] : 0.f;
#pragma unroll
    for (int off = 32; off; off >>= 1) v += __shfl_xor(v, off);
    if (lane == 0) out[0] = v * (1.0f / B_);
}

extern "C" void kernel_launch(void* const* d_in, const int* in_sizes, int n_in,
                              void* d_out, int out_size, void* d_ws, size_t ws_size,
                              hipStream_t stream) {
    const float* logits    = (const float*)d_in[0];   // [B,1,T,C] fp32
    const int*   text_lens = (const int*)d_in[1];     // [B] int32
    const int*   mel_lens  = (const int*)d_in[2];     // [B] int32
    float* out = (float*)d_out;

    const size_t PBF_BYTES  = (size_t)B_ * T_ * 512 * 2;          // 65,536,000
    const size_t tail_bytes = (size_t)B_ * T_ * 4 + 2 * B_ * 4 + 64;

    if (ws_size >= PBF_BYTES + tail_bytes) {
        unsigned short* pbf = (unsigned short*)d_ws;
        float* ls     = (float*)((char*)d_ws + PBF_BYTES);    // p0[t] per row
        float* lsums  = ls + (size_t)B_ * T_;
        float* losses = lsums + B_;
        k_prob<<<B_ * T_ / 4, 256, 0, stream>>>(logits, text_lens, pbf, ls);
        k_ctc2<<<B_, 128, 0, stream>>>(pbf, text_lens, mel_lens, ls, losses);
        k_final<<<1, 64, 0, stream>>>(losses, out);
    } else {
        float* ls     = (float*)d_ws;
        float* lsums  = ls + (size_t)B_ * T_;
        float* losses = lsums + B_;
        k_prob<<<B_ * T_ / 4, 256, 0, stream>>>(logits, text_lens, nullptr, ls);
        k_lsum<<<B_, 256, 0, stream>>>(ls, mel_lens, lsums);
        k_ctc_slow<<<B_, 64, 0, stream>>>(logits, text_lens, mel_lens, lsums, losses);
        k_final<<<1, 64, 0, stream>>>(losses, out);
    }
}